// Round 3
// baseline (267.826 us; speedup 1.0000x reference)
//
#include <hip/hip_runtime.h>

typedef __bf16 bf16;
typedef __bf16 bf16x8 __attribute__((ext_vector_type(8)));
typedef __bf16 bf16x4 __attribute__((ext_vector_type(4)));
typedef float f32x4 __attribute__((ext_vector_type(4)));
typedef unsigned int u32;

#define NB    2048
#define NM    26
#define NJP   27      // 26 K-chunks + 1 zero pad (unconditional prefetch)
#define NBLK  512     // grid size; all blocks co-resident (2/CU needed, ~4 fit)

__device__ __forceinline__ bf16x8 splat8(u32 p) {
  union { u32 u[4]; bf16x8 v; } s;
  s.u[0] = p; s.u[1] = p; s.u[2] = p; s.u[3] = p;
  return s.v;
}

__device__ __forceinline__ u32 dup16(float v) {
  union { bf16 h; unsigned short s; } cv; cv.h = (bf16)v;
  return (u32)cv.s * 0x10001u;
}

// manual grid barrier: monotone arrive-counter, system-scope fences (cross-XCD
// L2 writeback/invalidate). Counter zeroed by hipMemsetAsync before launch.
__device__ __forceinline__ void grid_barrier(u32* cnt, u32 target) {
  __syncthreads();
  if (threadIdx.x == 0) {
    __threadfence_system();   // release: make w1t/G2/out writes visible
    __hip_atomic_fetch_add(cnt, 1u, __ATOMIC_RELEASE, __HIP_MEMORY_SCOPE_SYSTEM);
    while (__hip_atomic_load(cnt, __ATOMIC_ACQUIRE, __HIP_MEMORY_SCOPE_SYSTEM) < target)
      __builtin_amdgcn_s_sleep(2);
    __threadfence_system();   // acquire: invalidate stale L1/L2 lines
  }
  __syncthreads();
}

// phase-B K-chunk step, barrier-free: B-frags for chunk J+1 prefetched straight
// from w1t (L2-resident, coalesced 16B/lane); A-scalars prefetched from `in`;
// compute chunk J from register buffer CUR.
#define STEP(CUR, NXT, J) do {                                                 \
  { int jn = ((J)+1 > 25) ? 25 : (J)+1;  /* chunk-26 weights are zero */       \
    sc[NXT][0] = dup16(spw[jn*32]);                                            \
    sc[NXT][1] = dup16(spw[jn*32 + 16]); }                                     \
  _Pragma("unroll")                                                            \
  for (int ni = 0; ni < 4; ++ni)                                               \
    B[NXT][ni] = *(const bf16x8*)(tb + (long)((J)+1)*2048 + ni*512);           \
  _Pragma("unroll")                                                            \
  for (int mi = 0; mi < 2; ++mi) {                                             \
    bf16x8 af = xf[mi] * splat8(sc[CUR][mi]);                                  \
    _Pragma("unroll")                                                          \
    for (int ni = 0; ni < 4; ++ni)                                             \
      acc[mi][ni] = __builtin_amdgcn_mfma_f32_16x16x32_bf16(af, B[CUR][ni],    \
                                                            acc[mi][ni], 0, 0, 0); \
  }                                                                            \
} while (0)

// phase-C K-step: M16 tile (single A frag), register double-buffer.
#define STEPG2(CUR, NXT, KN) do {                                              \
  A2[NXT] = *(const bf16x8*)(Ab + (long)(KN)*1024);                            \
  _Pragma("unroll")                                                            \
  for (int ni = 0; ni < 4; ++ni)                                               \
    B2[NXT][ni] = *(const bf16x8*)(tbc + (long)(KN)*2048 + ni*512);            \
  _Pragma("unroll")                                                            \
  for (int ni = 0; ni < 4; ++ni)                                               \
    acc2[ni] = __builtin_amdgcn_mfma_f32_16x16x32_bf16(A2[CUR], B2[CUR][ni],   \
                                                       acc2[ni], 0, 0, 0);     \
} while (0)

// ---------------- single fused kernel: prep | cin1+G | gemm2 -----------------
// Phase A: frag-linear weight tiles + out bias init (905,216 elems over
//          131,072 threads, <=7 each).
// Phase B: layer 1 + fused G. wave = 1 batch (32 rows), loops over both
//          cs-halves; barrier-free reg-dbuf K-loop; wave-private ldsT.
// Phase C: gemm2 out[b][128+h] += sum_K G2[b,K]*W2p[h,K]; 256 M16-tiles x
//          8 splits = 2048 wave-tasks; split-blocks bid%8-equal (same-XCD
//          atomics).
__global__ __launch_bounds__(256, 2) void fused(
    const float* __restrict__ in, const float* __restrict__ W1,
    const float* __restrict__ b1, const float* __restrict__ W2,
    const float* __restrict__ b2, bf16* __restrict__ w1t,
    bf16* __restrict__ w2t2, bf16* __restrict__ G2, float* __restrict__ out,
    u32* __restrict__ cnt)
{
  __shared__ __align__(16) bf16 ldsT[4][64*36];   // wave-private x1^T [i64][k32+pad]
  const int t = threadIdx.x;
  const int bid = blockIdx.x;
  const int lane = t & 63, w = t >> 6;
  const int lr = lane & 15, lq = lane >> 4;
  const int fo = lq*128 + lr*8;

  // ---------------- phase A: prep ----------------
  #pragma unroll
  for (int g = 0; g < 7; ++g) {
    int ge = g*131072 + bid*256 + t;
    if (ge < 110592) {                    // w1t tiles [cs(2)][c(NJP)], frag-linear
      int e = ge;
      int el = e & 7, plr = (e >> 3) & 15, plq = (e >> 7) & 3, ni = (e >> 9) & 3;
      int rest = e >> 11;
      int c = rest % NJP, cs_idx = rest / NJP;
      int h = cs_idx*64 + ni*16 + plr;
      int i = plq*8 + el;
      float v = (i < NM && c < NM) ? W1[h*(NM*NM) + i*NM + c] : 0.f;
      w1t[e] = (bf16)v;
    } else if (ge < 643072) {             // w2t2 tiles [cs(2)][kc(130)], frag-linear
      int e = ge - 110592;                // flatK = kc*32 + c  (kc=i, c=j)
      int el = e & 7, plr = (e >> 3) & 15, plq = (e >> 7) & 3, ni = (e >> 9) & 3;
      int rest = e >> 11;                 // [0, 260)
      int kc = rest % 130, cs_idx = rest / 130;
      int h = cs_idx*64 + ni*16 + plr;
      int c = plq*8 + el;
      float v = (kc < 128 && c < NM) ? W2[h*(128*NM) + kc*NM + c] : 0.f;
      w2t2[e] = (bf16)v;
    } else if (ge < 905216) {             // out[b][128+h] = 32*b2[h]
      int e = ge - 643072;                // [0, NB*128)
      int b = e >> 7, h = e & 127;
      out[b*256 + 128 + h] = 32.0f * b2[h];
    }
  }

  grid_barrier(cnt, NBLK);

  // ---------------- phase B: layer 1 + fused G ----------------
  {
    const int bw = bid*4 + w;                     // this wave's batch
    const float* bin = in + (long)bw*(NM*32);
    const float* spw = bin + lr;                  // + j*32 + mi*16 (k = mi*16+lr)

    // x0 A-frags direct from in (cs-independent): xf[mi][e] = x0[bw][lq*8+e][mi*16+lr]
    bf16x8 xf[2];
    #pragma unroll
    for (int mi = 0; mi < 2; ++mi)
      #pragma unroll
      for (int e = 0; e < 8; ++e) {
        int j = lq*8 + e;
        xf[mi][e] = (bf16)((j < NM) ? bin[j*32 + mi*16 + lr] : 0.f);
      }

    // B-frags for the G-step (cs-independent): x0[j][k]
    bf16x8 bg[2];
    #pragma unroll
    for (int nt = 0; nt < 2; ++nt) {
      int j = nt*16 + lr;
      bf16x8 v;
      #pragma unroll
      for (int e=0; e<8; ++e) v[e] = (bf16)0.f;
      if (j < NM) {
        const float* src = bin + j*32 + lq*8;
        f32x4 a = *(const f32x4*)src, c = *(const f32x4*)(src+4);
        #pragma unroll
        for (int e=0; e<4; ++e) { v[e] = (bf16)a[e]; v[4+e] = (bf16)c[e]; }
      }
      bg[nt] = v;
    }

    const long gbase = (long)(bw >> 5)*131072 + (bw & 31)*8;
    bf16* T = &ldsT[w][0];

    for (int csi = 0; csi < 2; ++csi) {
      const int cs = csi * 64;

      f32x4 acc[2][4];
      #pragma unroll
      for (int mi=0; mi<2; ++mi)
        #pragma unroll
        for (int ni=0; ni<4; ++ni) acc[mi][ni] = {0.f,0.f,0.f,0.f};

      const bf16* tb = w1t + (long)csi*NJP*2048 + fo;

      u32 sc[2][2];
      bf16x8 B[2][4];
      #pragma unroll
      for (int ni = 0; ni < 4; ++ni)
        B[0][ni] = *(const bf16x8*)(tb + ni*512);   // chunk 0
      sc[0][0] = dup16(spw[0]);  sc[0][1] = dup16(spw[16]);

      for (int jj = 0; jj < 13; ++jj) {
        STEP(0, 1, 2*jj);
        STEP(1, 0, 2*jj + 1);
      }

      float bias[4];
      #pragma unroll
      for (int ni=0; ni<4; ++ni) bias[ni] = b1[cs + ni*16 + lr];

      // out[bw][cs:cs+64] = k-sum of x1 + 32*bias
      #pragma unroll
      for (int ni=0; ni<4; ++ni) {
        float v = 0.f;
        #pragma unroll
        for (int mi=0; mi<2; ++mi)
          #pragma unroll
          for (int r=0; r<4; ++r) v += acc[mi][ni][r];
        v += __shfl_xor(v, 16, 64);
        v += __shfl_xor(v, 32, 64);
        if (lq == 0) out[bw*256 + cs + ni*16 + lr] = v + 32.0f * bias[ni];
      }

      // x1 (C-layout) -> wave-private LDS [i_local][k], row stride 36
      #pragma unroll
      for (int mi=0; mi<2; ++mi)
        #pragma unroll
        for (int ni=0; ni<4; ++ni) {
          bf16x4 pk;
          #pragma unroll
          for (int r=0; r<4; ++r) pk[r] = (bf16)(acc[mi][ni][r] + bias[ni]);
          *(bf16x4*)&T[(ni*16+lr)*36 + mi*16 + lq*4] = pk;
        }
      // no barrier: each wave reads only its own tile (lgkmcnt ordering)

      // G-MFMAs + tiled G2 stores
      #pragma unroll
      for (int mt = 0; mt < 4; ++mt) {
        bf16x8 ag = *(const bf16x8*)&T[(mt*16+lr)*36 + lq*8];
        #pragma unroll
        for (int nt = 0; nt < 2; ++nt) {
          f32x4 z = {0.f,0.f,0.f,0.f};
          f32x4 gq = __builtin_amdgcn_mfma_f32_16x16x32_bf16(ag, bg[nt], z, 0, 0, 0);
          const int jh = nt*2 + (lr >> 3), jl = lr & 7;
          #pragma unroll
          for (int r = 0; r < 4; ++r) {
            int i = cs + mt*16 + lq*4 + r;
            G2[gbase + (long)(i*4 + jh)*256 + jl] = (bf16)gq[r];
          }
        }
      }
    }
  }

  grid_barrier(cnt, 2*NBLK);

  // ---------------- phase C: gemm2 ----------------
  {
    const int s = bid >> 6;                     // 8 splits (bid%8 equal per tile)
    const int q64 = bid & 63;
    const int tile = q64*4 + w;                 // 0..255
    const int cs_idx = tile & 1, ms16 = tile >> 1;
    const int ms = ms16 >> 1, mif = ms16 & 1;
    const int kc0 = s*16;

    const bf16* Ab  = G2 + ((long)(ms*512 + lq)*32 + lr)*8 + mif*128;
    const bf16* tbc = w2t2 + (long)cs_idx*130*2048 + fo;

    f32x4 acc2[4];
    #pragma unroll
    for (int ni=0; ni<4; ++ni) acc2[ni] = {0.f,0.f,0.f,0.f};

    bf16x8 A2[2], B2[2][4];
    A2[0] = *(const bf16x8*)(Ab + (long)kc0*1024);
    #pragma unroll
    for (int ni=0; ni<4; ++ni)
      B2[0][ni] = *(const bf16x8*)(tbc + (long)kc0*2048 + ni*512);

    for (int jj = 0; jj < 8; ++jj) {
      STEPG2(0, 1, kc0 + 2*jj + 1);
      STEPG2(1, 0, kc0 + 2*jj + 2);
    }

    #pragma unroll
    for (int ni=0; ni<4; ++ni) {
      int h = cs_idx*64 + ni*16 + lr;
      #pragma unroll
      for (int r=0; r<4; ++r) {
        int b = ms16*16 + lq*4 + r;
        atomicAdd(&out[b*256 + 128 + h], acc2[ni][r]);
      }
    }
  }
}

// ---------------- launch ----------------
extern "C" void kernel_launch(void* const* d_in, const int* in_sizes, int n_in,
                              void* d_out, int out_size, void* d_ws, size_t ws_size,
                              hipStream_t stream) {
  const float* in = (const float*)d_in[0];
  const float* W1 = (const float*)d_in[1];
  const float* b1 = (const float*)d_in[2];
  const float* W2 = (const float*)d_in[3];
  const float* b2 = (const float*)d_in[4];
  float* out = (float*)d_out;

  char* ws = (char*)d_ws;
  bf16* w1t  = (bf16*)(ws);                 // 2*27*2048*2  = 221,184
  bf16* w2t2 = (bf16*)(ws + 1048576);       // 2*130*2048*2 = 1,064,960
  u32*  cnt  = (u32*) (ws + 3145728);       // 64 B barrier counter
  bf16* G2   = (bf16*)(ws + 4194304);       // 2048*4096*2  = 16,777,216 (end ~21 MB)

  hipMemsetAsync(cnt, 0, 64, stream);
  fused<<<NBLK, 256, 0, stream>>>(in, W1, b1, W2, b2, w1t, w2t2, G2, out, cnt);
}

// Round 4
// 112.842 us; speedup vs baseline: 2.3735x; 2.3735x over previous
//
#include <hip/hip_runtime.h>

typedef __bf16 bf16;
typedef __bf16 bf16x8 __attribute__((ext_vector_type(8)));
typedef __bf16 bf16x4 __attribute__((ext_vector_type(4)));
typedef float f32x4 __attribute__((ext_vector_type(4)));
typedef unsigned int u32;

#define NB    2048
#define NM    26
#define NJP   27      // 26 K-chunks + 1 zero pad (unconditional prefetch)

__device__ __forceinline__ bf16x8 splat8(u32 p) {
  union { u32 u[4]; bf16x8 v; } s;
  s.u[0] = p; s.u[1] = p; s.u[2] = p; s.u[3] = p;
  return s.v;
}

__device__ __forceinline__ u32 dup16(float v) {
  union { bf16 h; unsigned short s; } cv; cv.h = (bf16)v;
  return (u32)cv.s * 0x10001u;
}

// ---------------- prep: frag-linear weight tiles (no bias init) --------------
// Weight tiles FRAGMENT-LINEAR: in a 64x32 tile, element (r=ni*16+lr,
// c=lq*8+el) lives at ni*512 + lq*128 + lr*8 + el.
// 643,072 elems = 628 blocks * 256 thr * 4 strides exactly.
__global__ __launch_bounds__(256) void prep_all(
    const float* __restrict__ W1, const float* __restrict__ W2,
    bf16* __restrict__ w1t, bf16* __restrict__ w2t2)
{
  const int bid = blockIdx.x, t = threadIdx.x;
  #pragma unroll
  for (int g = 0; g < 4; ++g) {
    int ge = g*160768 + bid*256 + t;
    if (ge < 110592) {                    // w1t tiles [cs(2)][c(NJP)], frag-linear
      int e = ge;
      int el = e & 7, lr = (e >> 3) & 15, lq = (e >> 7) & 3, ni = (e >> 9) & 3;
      int rest = e >> 11;
      int c = rest % NJP, cs_idx = rest / NJP;
      int h = cs_idx*64 + ni*16 + lr;
      int i = lq*8 + el;
      float v = (i < NM && c < NM) ? W1[h*(NM*NM) + i*NM + c] : 0.f;
      w1t[e] = (bf16)v;
    } else {                              // w2t2 tiles [cs(2)][kc(130)], frag-linear
      int e = ge - 110592;                // flatK = kc*32 + c  (kc=i, c=j)
      int el = e & 7, lr = (e >> 3) & 15, lq = (e >> 7) & 3, ni = (e >> 9) & 3;
      int rest = e >> 11;                 // [0, 260)
      int kc = rest % 130, cs_idx = rest / 130;
      int h = cs_idx*64 + ni*16 + lr;
      int c = lq*8 + el;
      float v = (kc < 128 && c < NM) ? W2[h*(128*NM) + kc*NM + c] : 0.f;
      w2t2[e] = (bf16)v;
    }
  }
}

// phase-B K-chunk step, barrier-free: B-frags for chunk J+1 prefetched straight
// from w1t (L2-resident, coalesced 16B/lane); A-scalars prefetched from `in`;
// compute chunk J from register buffer CUR.
#define STEP(CUR, NXT, J) do {                                                 \
  { int jn = ((J)+1 > 25) ? 25 : (J)+1;  /* chunk-26 weights are zero */       \
    sc[NXT][0] = dup16(spw[jn*32]);                                            \
    sc[NXT][1] = dup16(spw[jn*32 + 16]); }                                     \
  _Pragma("unroll")                                                            \
  for (int ni = 0; ni < 4; ++ni)                                               \
    B[NXT][ni] = *(const bf16x8*)(tb + (long)((J)+1)*2048 + ni*512);           \
  _Pragma("unroll")                                                            \
  for (int mi = 0; mi < 2; ++mi) {                                             \
    bf16x8 af = xf[mi] * splat8(sc[CUR][mi]);                                  \
    _Pragma("unroll")                                                          \
    for (int ni = 0; ni < 4; ++ni)                                             \
      acc[mi][ni] = __builtin_amdgcn_mfma_f32_16x16x32_bf16(af, B[CUR][ni],    \
                                                            acc[mi][ni], 0, 0, 0); \
  }                                                                            \
} while (0)

// ---------------- layer 1 + fused G: wave = 1 batch (32 rows) x one cs-half ---
// XCD-matched mapping: blocks with bid%8==x handle ms-groups m8 with m8%8==x,
// so gemm2 blocks (same keying) read G2 from their own XCD's L2.
// Epilogue: swapped G-MFMA (A=x0, B=x1^T) puts j in the register index ->
// lane holds G[bw][i=cs+mt*16+lr][j=nt*16+lq*4+r], 4 contiguous flatK per
// store -> bf16x4 (8B) stores, 8 per wave.
__global__ __launch_bounds__(256, 4) void cin1G(
    const float* __restrict__ in, const bf16* __restrict__ w1t,
    const float* __restrict__ b1, bf16* __restrict__ G2, float* __restrict__ out)
{
  __shared__ __align__(16) bf16 ldsT[4][64*36];   // wave-private x1^T [i64][k32+pad]
  const int t = threadIdx.x;
  const int bid = blockIdx.x;
  const int lane = t & 63, w = t >> 6;
  // bid -> (strip, cs): XCD-chunked. x=bid%8; m8 = (u>>4)*8+x covers strips
  // [8*m8, 8*m8+7] (batches [32*m8, 32*m8+31]) entirely on XCD x.
  const int x = bid & 7, u = bid >> 3;
  const int m8 = (u >> 4)*8 + x;
  const int v = u & 15;
  const int strip = m8*8 + (v >> 1);
  const int cs_idx = v & 1, cs = cs_idx * 64;
  const int lr = lane & 15, lq = lane >> 4;
  const int fo = lq*128 + lr*8;
  const int bw = strip*4 + w;                     // this wave's batch

  const float* bin = in + (long)bw*(NM*32);
  const float* spw = bin + lr;                    // + j*32 + mi*16 (k = mi*16+lr)

  // x0 A-frags direct from in: xf[mi][e] = x0[bw][j=lq*8+e][k=mi*16+lr]
  bf16x8 xf[2];
  #pragma unroll
  for (int mi = 0; mi < 2; ++mi)
    #pragma unroll
    for (int e = 0; e < 8; ++e) {
      int j = lq*8 + e;
      xf[mi][e] = (bf16)((j < NM) ? bin[j*32 + mi*16 + lr] : 0.f);
    }

  f32x4 acc[2][4];
  #pragma unroll
  for (int mi=0; mi<2; ++mi)
    #pragma unroll
    for (int ni=0; ni<4; ++ni) acc[mi][ni] = {0.f,0.f,0.f,0.f};

  const bf16* tb = w1t + (long)cs_idx*NJP*2048 + fo;

  u32 sc[2][2];
  bf16x8 B[2][4];
  #pragma unroll
  for (int ni = 0; ni < 4; ++ni)
    B[0][ni] = *(const bf16x8*)(tb + ni*512);     // chunk 0
  sc[0][0] = dup16(spw[0]);  sc[0][1] = dup16(spw[16]);

  for (int jj = 0; jj < 13; ++jj) {
    STEP(0, 1, 2*jj);
    STEP(1, 0, 2*jj + 1);
  }

  float bias[4];
  #pragma unroll
  for (int ni=0; ni<4; ++ni) bias[ni] = b1[cs + ni*16 + lr];

  // out[bw][0:128] = k-sum of x1 + 32*bias
  #pragma unroll
  for (int ni=0; ni<4; ++ni) {
    float vv = 0.f;
    #pragma unroll
    for (int mi=0; mi<2; ++mi)
      #pragma unroll
      for (int r=0; r<4; ++r) vv += acc[mi][ni][r];
    vv += __shfl_xor(vv, 16, 64);
    vv += __shfl_xor(vv, 32, 64);
    if (lq == 0) out[bw*256 + cs + ni*16 + lr] = vv + 32.0f * bias[ni];
  }

  // x1 (C-layout) -> wave-private LDS [i_local][k], row stride 36
  bf16* T = &ldsT[w][0];
  #pragma unroll
  for (int mi=0; mi<2; ++mi)
    #pragma unroll
    for (int ni=0; ni<4; ++ni) {
      bf16x4 pk;
      #pragma unroll
      for (int r=0; r<4; ++r) pk[r] = (bf16)(acc[mi][ni][r] + bias[ni]);
      *(bf16x4*)&T[(ni*16+lr)*36 + mi*16 + lq*4] = pk;
    }
  // no barrier: each wave reads only its own tile (lgkmcnt ordering)

  // B-frags: x0[j][k] from in
  bf16x8 bg[2];
  #pragma unroll
  for (int nt = 0; nt < 2; ++nt) {
    int j = nt*16 + lr;
    bf16x8 vv;
    #pragma unroll
    for (int e=0; e<8; ++e) vv[e] = (bf16)0.f;
    if (j < NM) {
      const float* src = bin + j*32 + lq*8;
      f32x4 a = *(const f32x4*)src, c = *(const f32x4*)(src+4);
      #pragma unroll
      for (int e=0; e<4; ++e) { vv[e] = (bf16)a[e]; vv[4+e] = (bf16)c[e]; }
    }
    bg[nt] = vv;
  }
  // swapped G-MFMAs + vectorized tiled G2 stores
  const long gbase = (long)(bw >> 5)*131072 + (bw & 31)*8;
  #pragma unroll
  for (int mt = 0; mt < 4; ++mt) {
    bf16x8 ag = *(const bf16x8*)&T[(mt*16+lr)*36 + lq*8];
    #pragma unroll
    for (int nt = 0; nt < 2; ++nt) {
      f32x4 z = {0.f,0.f,0.f,0.f};
      f32x4 g = __builtin_amdgcn_mfma_f32_16x16x32_bf16(bg[nt], ag, z, 0, 0, 0);
      // lane holds G[bw][i=cs+mt*16+lr][j=nt*16+lq*4+r]
      bf16x4 pk;
      #pragma unroll
      for (int r = 0; r < 4; ++r) pk[r] = (bf16)g[r];
      const int kh = (cs + mt*16 + lr)*4 + nt*2 + (lq >> 1);
      *(bf16x4*)&G2[gbase + (long)kh*256 + (lq & 1)*4] = pk;
    }
  }
}

// ---------------- gemm2: out[b][128+h] += sum_K G[b][K]*W2p[h][K] -------------
// M=2048 b (tiles of 32), N=128 h, K=4096 flat; split-K x16; atomics into out
// (L2-resident). s==0 folds the +32*b2[h] bias (out is zeroed by harness).
// ms keyed to bid%8 -> reads G2 written by same XCD (L2-local).
#define STEPG(CUR, NXT, KN) do {                                               \
  _Pragma("unroll")                                                            \
  for (int mi = 0; mi < 2; ++mi)                                               \
    A[NXT][mi] = *(const bf16x8*)(Ab + (long)(KN)*1024 + mi*128);              \
  _Pragma("unroll")                                                            \
  for (int ni = 0; ni < 4; ++ni)                                               \
    B[NXT][ni] = *(const bf16x8*)(tbc + (long)(KN)*2048 + ni*512);             \
  _Pragma("unroll")                                                            \
  for (int mi = 0; mi < 2; ++mi)                                               \
    _Pragma("unroll")                                                          \
    for (int ni = 0; ni < 4; ++ni)                                             \
      acc[mi][ni] = __builtin_amdgcn_mfma_f32_16x16x32_bf16(A[CUR][mi],        \
                                  B[CUR][ni], acc[mi][ni], 0, 0, 0);           \
} while (0)

__global__ __launch_bounds__(256, 4) void gemm2(
    const bf16* __restrict__ G2, const bf16* __restrict__ w2t2,
    const float* __restrict__ b2, float* __restrict__ out)
{
  const int t = threadIdx.x;
  const int lane = t & 63, w = t >> 6;
  const int s = blockIdx.x >> 5;              // 16 splits; bid%8 == q32%8
  const int q32 = blockIdx.x & 31;
  const int x = q32 & 7, q = q32 >> 3;
  const int ms = x + q*16 + (w >> 1)*8;       // ms%8 == bid%8 -> XCD-local G2
  const int cs_idx = w & 1;
  const int lr = lane & 15, lq = lane >> 4;
  const int fo = lq*128 + lr*8;
  const int kc0 = s*8;

  const bf16* Ab  = G2 + ((long)(ms*512 + lq)*32 + lr)*8;
  const bf16* tbc = w2t2 + (long)cs_idx*130*2048 + fo;

  f32x4 acc[2][4];
  #pragma unroll
  for (int mi=0; mi<2; ++mi)
    #pragma unroll
    for (int ni=0; ni<4; ++ni) acc[mi][ni] = {0.f,0.f,0.f,0.f};

  bf16x8 A[2][2], B[2][4];
  #pragma unroll
  for (int mi=0; mi<2; ++mi)
    A[0][mi] = *(const bf16x8*)(Ab + (long)kc0*1024 + mi*128);
  #pragma unroll
  for (int ni=0; ni<4; ++ni)
    B[0][ni] = *(const bf16x8*)(tbc + (long)kc0*2048 + ni*512);

  for (int jj = 0; jj < 4; ++jj) {
    STEPG(0, 1, kc0 + 2*jj + 1);
    STEPG(1, 0, kc0 + 2*jj + 2);
  }

  if (s == 0) {                               // fold +32*b2[h] (out starts at 0)
    #pragma unroll
    for (int ni=0; ni<4; ++ni) {
      float bv = 32.0f * b2[cs_idx*64 + ni*16 + lr];
      #pragma unroll
      for (int mi=0; mi<2; ++mi)
        #pragma unroll
        for (int r=0; r<4; ++r) acc[mi][ni][r] += bv;
    }
  }

  #pragma unroll
  for (int mi=0; mi<2; ++mi)
    #pragma unroll
    for (int ni=0; ni<4; ++ni) {
      int h = cs_idx*64 + ni*16 + lr;
      #pragma unroll
      for (int r=0; r<4; ++r) {
        int b = ms*32 + mi*16 + lq*4 + r;
        atomicAdd(&out[b*256 + 128 + h], acc[mi][ni][r]);
      }
    }
}

// ---------------- launch ----------------
extern "C" void kernel_launch(void* const* d_in, const int* in_sizes, int n_in,
                              void* d_out, int out_size, void* d_ws, size_t ws_size,
                              hipStream_t stream) {
  const float* in = (const float*)d_in[0];
  const float* W1 = (const float*)d_in[1];
  const float* b1 = (const float*)d_in[2];
  const float* W2 = (const float*)d_in[3];
  const float* b2 = (const float*)d_in[4];
  float* out = (float*)d_out;

  char* ws = (char*)d_ws;
  bf16* w1t  = (bf16*)(ws);                 // 2*27*2048*2  = 221,184
  bf16* w2t2 = (bf16*)(ws + 1048576);       // 2*130*2048*2 = 1,064,960
  bf16* G2   = (bf16*)(ws + 4194304);       // 2048*4096*2  = 16,777,216 (end ~21 MB)

  prep_all<<<628,  256, 0, stream>>>(W1, W2, w1t, w2t2);
  cin1G   <<<1024, 256, 0, stream>>>(in, w1t, b1, G2, out);
  gemm2   <<<512,  256, 0, stream>>>(G2, w2t2, b2, out);
}